// Round 15
// baseline (148.194 us; speedup 1.0000x reference)
//
#include <hip/hip_runtime.h>

typedef unsigned short u16;
typedef unsigned int   u32;
typedef __attribute__((ext_vector_type(8))) short bf16x8;
typedef __attribute__((ext_vector_type(8))) unsigned short u16x8;
typedef __attribute__((ext_vector_type(4))) float f32x4;

#define NB   16
#define NPTS 4096
#define SPTS 1024
#define BNT  65536   // NB*NPTS

#define G2L(src, dst) __builtin_amdgcn_global_load_lds( \
    (const __attribute__((address_space(1))) void*)(src), \
    (__attribute__((address_space(3))) void*)(dst), 16, 0, 0)

__device__ __forceinline__ float bf2f(u16 u){ return __uint_as_float(((u32)u)<<16); }
__device__ __forceinline__ u16 f2bf(float f){
  u32 u = __float_as_uint(f);
  return (u16)((u + 0x7FFFu + ((u>>16)&1u))>>16);
}

// ---------------- W fp32 -> bf16 ----------------
__global__ __launch_bounds__(256) void convw_k(const float* __restrict__ w1, const float* __restrict__ w2,
                                               u16* __restrict__ w1b, u16* __restrict__ w2b){
  int i = blockIdx.x*256 + threadIdx.x;           // 131072 total
  if (i < 98304) w1b[i] = f2bf(w1[i]);
  else { int j = i - 98304; w2b[j] = f2bf(w2[j]); }
}

// ---------------- (B,C,S) fp32 -> rows (b*S+s)*ostride + c, bf16 ----------------
__global__ __launch_bounds__(256) void transpose_k(const float* __restrict__ in, u16* __restrict__ out,
                                                   int C, int S, int ostride){
  __shared__ float tl[64][65];
  int t = threadIdx.x;
  int b = blockIdx.y;
  int s0 = blockIdx.x * 64;
  for (int ct = 0; ct < C; ct += 64){
    __syncthreads();
    for (int i = t; i < 4096; i += 256){
      int sl = i & 63, cl = i >> 6;
      tl[sl][cl] = in[((size_t)b*C + ct + cl)*S + s0 + sl];
    }
    __syncthreads();
    for (int i = t; i < 4096; i += 256){
      int cl = i & 63, sl = i >> 6;
      out[((size_t)b*S + s0 + sl)*ostride + ct + cl] = f2bf(tl[sl][cl]);
    }
  }
}

// ---------------- 3-NN search (R4/R13-proven) + interp -> X cols [128,384) ----------------
__global__ __launch_bounds__(512) void knn_k(const float* __restrict__ xyz1, const float* __restrict__ xyz2,
                                             const u16* __restrict__ p2t, u16* __restrict__ X){
  __shared__ float4 sxyz[SPTS];          // 16 KB
  __shared__ float  pd[8][3][64];
  __shared__ int    pi[8][3][64];
  __shared__ float  swts[3][64];
  __shared__ int    sidx[3][64];
  int t  = threadIdx.x;
  int b  = blockIdx.x >> 6;
  int n0 = (blockIdx.x & 63) << 6;
  const float* x2b = xyz2 + (size_t)b*3*SPTS;
  for (int s = t; s < SPTS; s += 512)
    sxyz[s] = make_float4(x2b[s], x2b[SPTS+s], x2b[2*SPTS+s], 0.f);
  int q = t & 63, g = t >> 6;
  const float* x1b = xyz1 + (size_t)b*3*NPTS;
  int n = n0 + q;
  float qx = x1b[n], qy = x1b[NPTS+n], qz = x1b[2*NPTS+n];
  __syncthreads();

  float d0=3.4e38f, d1=3.4e38f, d2=3.4e38f;
  int   i0=0, i1=0, i2=0;
  int sBeg = g << 7, sEnd = sBeg + 128;
  for (int s = sBeg; s < sEnd; ++s){
    float4 p = sxyz[s];
    float dist;
    {
      #pragma clang fp contract(off)
      float dx = qx - p.x, dy = qy - p.y, dz = qz - p.z;
      dist = ((dx*dx) + (dy*dy)) + (dz*dz);   // match numpy rounding exactly (no fma)
    }
    if (dist < d2){
      bool c1 = dist < d1, c0 = dist < d0;
      d2 = c1 ? d1 : dist;                 i2 = c1 ? i1 : s;
      float nd1 = c1 ? (c0 ? d0 : dist) : d1;
      int   ni1 = c1 ? (c0 ? i0 : s)    : i1;
      d0 = c0 ? dist : d0;                 i0 = c0 ? s : i0;
      d1 = nd1;                            i1 = ni1;
    }
  }
  pd[g][0][q]=d0; pd[g][1][q]=d1; pd[g][2][q]=d2;
  pi[g][0][q]=i0; pi[g][1][q]=i1; pi[g][2][q]=i2;
  __syncthreads();

  if (t < 64){
    float m0=3.4e38f, m1=3.4e38f, m2=3.4e38f;
    int   j0=0, j1=0, j2=0;
    #pragma unroll
    for (int gg = 0; gg < 8; ++gg){
      #pragma unroll
      for (int p = 0; p < 3; ++p){
        float dist = pd[gg][p][t]; int s = pi[gg][p][t];
        if (dist < m2){
          bool c1 = dist < m1, c0 = dist < m0;
          m2 = c1 ? m1 : dist;                 j2 = c1 ? j1 : s;
          float nd1 = c1 ? (c0 ? m0 : dist) : m1;
          int   ni1 = c1 ? (c0 ? j0 : s)    : j1;
          m0 = c0 ? dist : m0;                 j0 = c0 ? s : j0;
          m1 = nd1;                            j1 = ni1;
        }
      }
    }
    float r0 = 1.f/(m0 + 1e-8f), r1 = 1.f/(m1 + 1e-8f), r2 = 1.f/(m2 + 1e-8f);
    float rs = (r0 + r1) + r2;
    swts[0][t] = r0/rs; swts[1][t] = r1/rs; swts[2][t] = r2/rs;
    sidx[0][t] = j0;    sidx[1][t] = j1;    sidx[2][t] = j2;
  }
  __syncthreads();

  int w = t >> 6, lane = t & 63;
  for (int qq = w*8; qq < w*8 + 8; ++qq){
    float wa = swts[0][qq], wb = swts[1][qq], wc = swts[2][qq];
    int   j0 = sidx[0][qq], j1 = sidx[1][qq], j2 = sidx[2][qq];
    const ushort4 u0 = *(const ushort4*)(p2t + (((size_t)b*SPTS + j0)<<8) + (lane<<2));
    const ushort4 u1 = *(const ushort4*)(p2t + (((size_t)b*SPTS + j1)<<8) + (lane<<2));
    const ushort4 u2 = *(const ushort4*)(p2t + (((size_t)b*SPTS + j2)<<8) + (lane<<2));
    ushort4 ov;
    ov.x = f2bf(wa*bf2f(u0.x) + wb*bf2f(u1.x) + wc*bf2f(u2.x));
    ov.y = f2bf(wa*bf2f(u0.y) + wb*bf2f(u1.y) + wc*bf2f(u2.y));
    ov.z = f2bf(wa*bf2f(u0.z) + wb*bf2f(u1.z) + wc*bf2f(u2.z));
    ov.w = f2bf(wa*bf2f(u0.w) + wb*bf2f(u1.w) + wc*bf2f(u2.w));
    *(ushort4*)(X + ((size_t)b*NPTS + n0 + qq)*384 + 128 + (lane<<2)) = ov;
  }
}

// ======== GEMM1: BM=128, BN=256, BK=32, 2-phase dbuf w/ __syncthreads (48KB -> 3 blocks/CU) ========
// Swizzle (BK=32, 64B rows): slot ^= (row>>1)&3  [R10-proven conflict-free]. R14 epilogue.
__global__ __launch_bounds__(256) void gemm1_k(const u16* __restrict__ A, const u16* __restrict__ Bw,
                                               u16* __restrict__ Cc,
                                               float* __restrict__ psum, float* __restrict__ psq){
  __shared__ u16 lA[2][128*32];   // 8 KB each (sums/sqs alias after K-loop)
  __shared__ u16 lB[2][256*32];   // 16 KB each (bounce alias after K-loop)
  float* sums = (float*)lA;
  float* sqs  = sums + 256;
  int t = threadIdx.x, lane = t & 63, wid = t >> 6;
  int rowBase = blockIdx.x << 7;            // 128 rows/block, grid 512
  int wm = wid >> 1, wn = wid & 1;

  const char* pA[2]; int dAo[2];
  #pragma unroll
  for (int j = 0; j < 2; ++j){
    int L = j*4096 + t*16;
    int row = L >> 6, kb = L & 63;
    int kbs = kb ^ (((row >> 1) & 3) << 4);
    pA[j] = (const char*)A + (size_t)(rowBase + row)*768 + kbs;
    dAo[j] = j*4096 + wid*1024;
  }
  const char* pB[4]; int dBo[4];
  #pragma unroll
  for (int j = 0; j < 4; ++j){
    int L = j*4096 + t*16;
    int row = L >> 6, kb = L & 63;
    int kbs = kb ^ (((row >> 1) & 3) << 4);
    pB[j] = (const char*)Bw + (size_t)row*768 + kbs;
    dBo[j] = j*4096 + wid*1024;
  }

  f32x4 z = {0.f,0.f,0.f,0.f};
  f32x4 acc[4][8];
  #pragma unroll
  for (int m = 0; m < 4; ++m)
    #pragma unroll
    for (int n = 0; n < 8; ++n) acc[m][n] = z;

  // prologue: stage tile 0 -> buf0
  #pragma unroll
  for (int j = 0; j < 2; ++j) G2L(pA[j], (char*)lA[0] + dAo[j]);
  #pragma unroll
  for (int j = 0; j < 4; ++j) G2L(pB[j], (char*)lB[0] + dBo[j]);
  __syncthreads();

  #pragma unroll
  for (int kt = 0; kt < 12; ++kt){
    const int cur = kt & 1;
    if (kt < 11){                           // prefetch next tile before compute
      size_t ko = (size_t)(kt + 1) * 64;
      #pragma unroll
      for (int j = 0; j < 2; ++j) G2L(pA[j] + ko, (char*)lA[cur^1] + dAo[j]);
      #pragma unroll
      for (int j = 0; j < 4; ++j) G2L(pB[j] + ko, (char*)lB[cur^1] + dBo[j]);
    }
    bf16x8 af[4];
    #pragma unroll
    for (int m = 0; m < 4; ++m){
      int row = wm*64 + m*16 + (lane & 15);
      int kb = ((lane >> 4) << 4) ^ (((row >> 1) & 3) << 4);
      af[m] = *(const bf16x8*)((const char*)lA[cur] + row*64 + kb);
    }
    #pragma unroll
    for (int n = 0; n < 8; ++n){
      int row = wn*128 + n*16 + (lane & 15);
      int kb = ((lane >> 4) << 4) ^ (((row >> 1) & 3) << 4);
      bf16x8 bv = *(const bf16x8*)((const char*)lB[cur] + row*64 + kb);
      #pragma unroll
      for (int m = 0; m < 4; ++m)
        acc[m][n] = __builtin_amdgcn_mfma_f32_16x16x32_bf16(af[m], bv, acc[m][n], 0, 0, 0);
    }
    __syncthreads();                        // prefetch landed; buf[cur] free for restage
  }

  // ---- epilogue (R14-proven): shfl-reduced stats + coalesced psum + LDS-bounce C-store ----
  sums[t] = 0.f; sqs[t] = 0.f;
  __syncthreads();
  int colb = wn*128 + (lane & 15);
  #pragma unroll
  for (int n = 0; n < 8; ++n){
    float s = 0.f, q = 0.f;
    #pragma unroll
    for (int m = 0; m < 4; ++m){
      #pragma unroll
      for (int r = 0; r < 4; ++r){
        float v = acc[m][n][r];
        s += v; q += v*v;
      }
    }
    s += __shfl_xor(s, 16); s += __shfl_xor(s, 32);
    q += __shfl_xor(q, 16); q += __shfl_xor(q, 32);
    if (lane < 16){
      atomicAdd(&sums[colb + n*16], s);
      atomicAdd(&sqs [colb + n*16], q);
    }
  }
  __syncthreads();
  psum[(size_t)blockIdx.x*256 + t] = sums[t];
  psq [(size_t)blockIdx.x*256 + t] = sqs[t];

  u16* bb = (u16*)lB;                         // 32 KB = [64][256] bf16
  int rl0 = ((lane >> 4) << 2);
  #pragma unroll
  for (int h = 0; h < 2; ++h){
    __syncthreads();
    if (wm == h){
      #pragma unroll
      for (int m = 0; m < 4; ++m)
        #pragma unroll
        for (int n = 0; n < 8; ++n)
          #pragma unroll
          for (int r = 0; r < 4; ++r)
            bb[(m*16 + rl0 + r)*256 + colb + n*16] = f2bf(acc[m][n][r]);
    }
    __syncthreads();
    u16* dst = Cc + (size_t)(rowBase + h*64)*256;
    #pragma unroll
    for (int i = 0; i < 8; ++i)
      *(u16x8*)(dst + i*2048 + t*8) = *(const u16x8*)(bb + i*2048 + t*8);
  }
}

// ======== GEMM2: BM=128, BN=128, BK=32, 2-phase dbuf w/ __syncthreads (33KB -> 4 blocks/CU) ========
// A = Y1 with fused BN1+relu reg-staging (R5-proven dbuf pattern: load regs + G2L B early,
// transform+ds_write to next buffer after compute, then __syncthreads).
__global__ __launch_bounds__(256) void gemm2_k(const u16* __restrict__ A, const u16* __restrict__ Bw,
                                               u16* __restrict__ Cc,
                                               const float* __restrict__ sc, const float* __restrict__ sh,
                                               float* __restrict__ psum, float* __restrict__ psq){
  const int K = 256;
  // L bytes: [0,8192) lA0, [8192,16384) lA1, [16384,24576) lB0, [24576,32768) lB1; bounce = all 32KB
  __shared__ u16 L[16384];
  __shared__ float sums[128], sqs[128];
  int t = threadIdx.x, lane = t & 63, wid = t >> 6;
  int rowBase = blockIdx.x << 7;              // 128 rows/block, grid 512
  int wm = wid >> 1, wn = wid & 1;

  const char* pB[2]; int dBo[2];
  #pragma unroll
  for (int j = 0; j < 2; ++j){
    int Lo = j*4096 + t*16;
    int row = Lo >> 6, kb = Lo & 63;
    int kbs = kb ^ (((row >> 1) & 3) << 4);
    pB[j] = (const char*)Bw + ((size_t)row*K)*2 + kbs;
    dBo[j] = j*4096 + wid*1024;               // + 16384 + buf*8192 at issue
  }
  // A fused staging: row = t&127, k-half h = t>>7 (wave-uniform) -> 16 ch/thread/tile
  int arow = t & 127, h = t >> 7;
  const u16* pArow = A + (size_t)(rowBase + arow)*K + h*16;
  int asw = ((arow >> 1) & 3) << 4;
  int wAo0 = arow*64 + ((h*32      ) ^ asw);  // + buf*8192
  int wAo1 = arow*64 + ((h*32 + 16 ) ^ asw);

  f32x4 z = {0.f,0.f,0.f,0.f};
  f32x4 acc[4][4];
  #pragma unroll
  for (int m = 0; m < 4; ++m)
    #pragma unroll
    for (int n = 0; n < 4; ++n) acc[m][n] = z;

  // prologue: tile 0 -> buf0
  {
    u16x8 y0 = *(const u16x8*)(pArow);
    u16x8 y1 = *(const u16x8*)(pArow + 8);
    #pragma unroll
    for (int j = 0; j < 2; ++j) G2L(pB[j], (char*)L + 16384 + dBo[j]);
    int k0 = h*16;
    bf16x8 o0, o1;
    #pragma unroll
    for (int j = 0; j < 8; ++j){
      float v = bf2f((u16)y0[j]) * sc[k0 + j] + sh[k0 + j];
      o0[j] = (short)f2bf(fmaxf(v, 0.f));
    }
    #pragma unroll
    for (int j = 0; j < 8; ++j){
      float v = bf2f((u16)y1[j]) * sc[k0 + 8 + j] + sh[k0 + 8 + j];
      o1[j] = (short)f2bf(fmaxf(v, 0.f));
    }
    *(bf16x8*)((char*)L + wAo0) = o0;
    *(bf16x8*)((char*)L + wAo1) = o1;
  }
  __syncthreads();

  #pragma unroll
  for (int kt = 0; kt < 8; ++kt){
    const int cur = kt & 1;
    u16x8 ny0 = {}, ny1 = {};
    if (kt < 7){
      ny0 = *(const u16x8*)(pArow + (kt+1)*32);
      ny1 = *(const u16x8*)(pArow + (kt+1)*32 + 8);
      size_t ko = (size_t)(kt + 1) * 64;
      #pragma unroll
      for (int j = 0; j < 2; ++j) G2L(pB[j] + ko, (char*)L + 16384 + (cur^1)*8192 + dBo[j]);
    }
    bf16x8 af[4];
    #pragma unroll
    for (int m = 0; m < 4; ++m){
      int row = wm*64 + m*16 + (lane & 15);
      int kb = ((lane >> 4) << 4) ^ (((row >> 1) & 3) << 4);
      af[m] = *(const bf16x8*)((const char*)L + cur*8192 + row*64 + kb);
    }
    #pragma unroll
    for (int n = 0; n < 4; ++n){
      int row = wn*64 + n*16 + (lane & 15);
      int kb = ((lane >> 4) << 4) ^ (((row >> 1) & 3) << 4);
      bf16x8 bv = *(const bf16x8*)((const char*)L + 16384 + cur*8192 + row*64 + kb);
      #pragma unroll
      for (int m = 0; m < 4; ++m)
        acc[m][n] = __builtin_amdgcn_mfma_f32_16x16x32_bf16(af[m], bv, acc[m][n], 0, 0, 0);
    }
    if (kt < 7){
      int k0 = (kt+1)*32 + h*16;
      bf16x8 o0, o1;
      #pragma unroll
      for (int j = 0; j < 8; ++j){
        float v = bf2f((u16)ny0[j]) * sc[k0 + j] + sh[k0 + j];
        o0[j] = (short)f2bf(fmaxf(v, 0.f));
      }
      #pragma unroll
      for (int j = 0; j < 8; ++j){
        float v = bf2f((u16)ny1[j]) * sc[k0 + 8 + j] + sh[k0 + 8 + j];
        o1[j] = (short)f2bf(fmaxf(v, 0.f));
      }
      *(bf16x8*)((char*)L + (cur^1)*8192 + wAo0) = o0;
      *(bf16x8*)((char*)L + (cur^1)*8192 + wAo1) = o1;
    }
    __syncthreads();
  }

  // ---- epilogue: stats + full-tile bounce (L = 32KB = [128][128] bf16) ----
  if (t < 128){ sums[t] = 0.f; sqs[t] = 0.f; }
  __syncthreads();
  int colb = wn*64 + (lane & 15);
  int rl0 = ((lane >> 4) << 2);
  #pragma unroll
  for (int n = 0; n < 4; ++n){
    float s = 0.f, q = 0.f;
    #pragma unroll
    for (int m = 0; m < 4; ++m){
      #pragma unroll
      for (int r = 0; r < 4; ++r){
        float v = acc[m][n][r];
        L[(wm*64 + m*16 + rl0 + r)*128 + colb + n*16] = f2bf(v);
        s += v; q += v*v;
      }
    }
    s += __shfl_xor(s, 16); s += __shfl_xor(s, 32);
    q += __shfl_xor(q, 16); q += __shfl_xor(q, 32);
    if (lane < 16){
      atomicAdd(&sums[colb + n*16], s);
      atomicAdd(&sqs [colb + n*16], q);
    }
  }
  __syncthreads();
  if (t < 128){
    psum[(size_t)blockIdx.x*128 + t] = sums[t];
    psq [(size_t)blockIdx.x*128 + t] = sqs[t];
  }
  u16* dst = Cc + (size_t)rowBase*128;
  #pragma unroll
  for (int i = 0; i < 8; ++i)
    *(u16x8*)(dst + i*2048 + t*8) = *(const u16x8*)(L + i*2048 + t*8);
}

// ---------------- reduce partials [bid][ch] -> per-channel BN scale/shift (8 ch per block) ----------------
__global__ __launch_bounds__(256) void finalize2_k(const float* __restrict__ psum, const float* __restrict__ psq,
                                                   const float* __restrict__ g, const float* __restrict__ bet,
                                                   float* __restrict__ sc, float* __restrict__ sh,
                                                   int C, int NBLK){
  __shared__ float ls[256][8], lq[256][8];
  int c0 = blockIdx.x*8, t = threadIdx.x;
  float s[8], q[8];
  #pragma unroll
  for (int j = 0; j < 8; ++j){ s[j] = 0.f; q[j] = 0.f; }
  for (int rb = t; rb < NBLK; rb += 256){
    const float* ps = psum + (size_t)rb*C + c0;
    const float* pq = psq  + (size_t)rb*C + c0;
    #pragma unroll
    for (int j = 0; j < 8; ++j){ s[j] += ps[j]; q[j] += pq[j]; }
  }
  #pragma unroll
  for (int j = 0; j < 8; ++j){ ls[t][j] = s[j]; lq[t][j] = q[j]; }
  __syncthreads();
  for (int off = 128; off; off >>= 1){
    if (t < off){
      #pragma unroll
      for (int j = 0; j < 8; ++j){ ls[t][j] += ls[t+off][j]; lq[t][j] += lq[t+off][j]; }
    }
    __syncthreads();
  }
  if (t < 8){
    int c = c0 + t;
    const float inv = 1.f/65536.f;
    float mean = ls[0][t]*inv;
    float var  = lq[0][t]*inv - mean*mean;
    float rstd = rsqrtf(var + 1e-5f);
    float scl  = g[c]*rstd;
    sc[c] = scl;
    sh[c] = bet[c] - mean*scl;
  }
}

// ---------------- BN2 + relu + transpose (BN,128) -> (B,128,N) fp32 out ----------------
__global__ __launch_bounds__(256) void finalout_k(const u16* __restrict__ y2, const float* __restrict__ sc,
                                                  const float* __restrict__ sh, float* __restrict__ out){
  __shared__ float tl[128][65];
  int t  = threadIdx.x;
  int b  = blockIdx.x >> 6;
  int n0 = (blockIdx.x & 63) << 6;
  for (int i = t; i < 8192; i += 256){
    int r = i >> 7, c = i & 127;
    float v = bf2f(y2[((size_t)b*NPTS + n0 + r)*128 + c]);
    v = fmaxf(v*sc[c] + sh[c], 0.f);
    tl[c][r] = v;
  }
  __syncthreads();
  for (int i = t; i < 8192; i += 256){
    int o = i >> 6, j = i & 63;
    out[(size_t)b*128*NPTS + (size_t)o*NPTS + n0 + j] = tl[o][j];
  }
}

extern "C" void kernel_launch(void* const* d_in, const int* in_sizes, int n_in,
                              void* d_out, int out_size, void* d_ws, size_t ws_size,
                              hipStream_t stream) {
  const float* xyz1    = (const float*)d_in[0];
  const float* xyz2    = (const float*)d_in[1];
  const float* points1 = (const float*)d_in[2];
  const float* points2 = (const float*)d_in[3];
  const float* w1      = (const float*)d_in[4];
  // d_in[5] = b1 (cancels in BN)
  const float* g1      = (const float*)d_in[6];
  const float* beta1   = (const float*)d_in[7];
  const float* w2      = (const float*)d_in[8];
  // d_in[9] = b2 (cancels in BN)
  const float* g2      = (const float*)d_in[10];
  const float* beta2   = (const float*)d_in[11];

  char* ws = (char*)d_ws;
  u16*  X    = (u16*)ws;                          // BN x 384 bf16 = 50,331,648   (dead after gemm1)
  u16*  Y2   = (u16*)ws;                          // alias X: BN x 128 bf16
  u16*  Y1   = (u16*)(ws + 50331648);             // BN x 256 bf16 = 33,554,432
  u16*  p2t  = (u16*)(ws + 83886080);             // B x S x 256 bf16 = 8,388,608 (dead after knn)
  u16*  w1b  = (u16*)(ws + 92274688);             // 196,608
  u16*  w2b  = (u16*)(ws + 92471296);             // 65,536
  float* psum1 = (float*)(ws + 83886080);         // [512][256] = 512KB, alias p2t (dead after knn)
  float* psq1  = (float*)(ws + 84934656);         // 512KB
  float* psum2 = (float*)(ws + 85983232);         // [512][128] = 256KB
  float* psq2  = (float*)(ws + 86507520);         // 256KB
  float* sc1   = (float*)(ws + 87031808);
  float* sh1   = (float*)(ws + 87032832);
  float* sc2   = (float*)(ws + 87033856);
  float* sh2   = (float*)(ws + 87034368);

  convw_k<<<512, 256, 0, stream>>>(w1, w2, w1b, w2b);
  transpose_k<<<dim3(64, 16), 256, 0, stream>>>(points1, X,   128, NPTS, 384);
  transpose_k<<<dim3(16, 16), 256, 0, stream>>>(points2, p2t, 256, SPTS, 256);
  knn_k<<<1024, 512, 0, stream>>>(xyz1, xyz2, p2t, X);
  gemm1_k<<<512, 256, 0, stream>>>(X, w1b, Y1, psum1, psq1);
  finalize2_k<<<32, 256, 0, stream>>>(psum1, psq1, g1, beta1, sc1, sh1, 256, 512);
  gemm2_k<<<512, 256, 0, stream>>>(Y1, w2b, Y2, sc1, sh1, psum2, psq2);
  finalize2_k<<<16, 256, 0, stream>>>(psum2, psq2, g2, beta2, sc2, sh2, 128, 512);
  finalout_k<<<1024, 256, 0, stream>>>(Y2, sc2, sh2, (float*)d_out);
}

// Round 16
// 144.037 us; speedup vs baseline: 1.0289x; 1.0289x over previous
//
#include <hip/hip_runtime.h>

typedef unsigned short u16;
typedef unsigned int   u32;
typedef __attribute__((ext_vector_type(8))) short bf16x8;
typedef __attribute__((ext_vector_type(8))) unsigned short u16x8;
typedef __attribute__((ext_vector_type(4))) float f32x4;

#define NB   16
#define NPTS 4096
#define SPTS 1024
#define BNT  65536   // NB*NPTS

#define G2L(src, dst) __builtin_amdgcn_global_load_lds( \
    (const __attribute__((address_space(1))) void*)(src), \
    (__attribute__((address_space(3))) void*)(dst), 16, 0, 0)

__device__ __forceinline__ float bf2f(u16 u){ return __uint_as_float(((u32)u)<<16); }
__device__ __forceinline__ u16 f2bf(float f){
  u32 u = __float_as_uint(f);
  return (u16)((u + 0x7FFFu + ((u>>16)&1u))>>16);
}

// ---------------- W fp32 -> bf16 ----------------
__global__ __launch_bounds__(256) void convw_k(const float* __restrict__ w1, const float* __restrict__ w2,
                                               u16* __restrict__ w1b, u16* __restrict__ w2b){
  int i = blockIdx.x*256 + threadIdx.x;           // 131072 total
  if (i < 98304) w1b[i] = f2bf(w1[i]);
  else { int j = i - 98304; w2b[j] = f2bf(w2[j]); }
}

// ---------------- (B,C,S) fp32 -> rows (b*S+s)*ostride + c, bf16 ----------------
__global__ __launch_bounds__(256) void transpose_k(const float* __restrict__ in, u16* __restrict__ out,
                                                   int C, int S, int ostride){
  __shared__ float tl[64][65];
  int t = threadIdx.x;
  int b = blockIdx.y;
  int s0 = blockIdx.x * 64;
  for (int ct = 0; ct < C; ct += 64){
    __syncthreads();
    for (int i = t; i < 4096; i += 256){
      int sl = i & 63, cl = i >> 6;
      tl[sl][cl] = in[((size_t)b*C + ct + cl)*S + s0 + sl];
    }
    __syncthreads();
    for (int i = t; i < 4096; i += 256){
      int cl = i & 63, sl = i >> 6;
      out[((size_t)b*S + s0 + sl)*ostride + ct + cl] = f2bf(tl[sl][cl]);
    }
  }
}

// ---------------- 3-NN search (R4/R13-proven) + interp -> X cols [128,384) ----------------
__global__ __launch_bounds__(512) void knn_k(const float* __restrict__ xyz1, const float* __restrict__ xyz2,
                                             const u16* __restrict__ p2t, u16* __restrict__ X){
  __shared__ float4 sxyz[SPTS];          // 16 KB
  __shared__ float  pd[8][3][64];
  __shared__ int    pi[8][3][64];
  __shared__ float  swts[3][64];
  __shared__ int    sidx[3][64];
  int t  = threadIdx.x;
  int b  = blockIdx.x >> 6;
  int n0 = (blockIdx.x & 63) << 6;
  const float* x2b = xyz2 + (size_t)b*3*SPTS;
  for (int s = t; s < SPTS; s += 512)
    sxyz[s] = make_float4(x2b[s], x2b[SPTS+s], x2b[2*SPTS+s], 0.f);
  int q = t & 63, g = t >> 6;
  const float* x1b = xyz1 + (size_t)b*3*NPTS;
  int n = n0 + q;
  float qx = x1b[n], qy = x1b[NPTS+n], qz = x1b[2*NPTS+n];
  __syncthreads();

  float d0=3.4e38f, d1=3.4e38f, d2=3.4e38f;
  int   i0=0, i1=0, i2=0;
  int sBeg = g << 7, sEnd = sBeg + 128;
  for (int s = sBeg; s < sEnd; ++s){
    float4 p = sxyz[s];
    float dist;
    {
      #pragma clang fp contract(off)
      float dx = qx - p.x, dy = qy - p.y, dz = qz - p.z;
      dist = ((dx*dx) + (dy*dy)) + (dz*dz);   // match numpy rounding exactly (no fma)
    }
    if (dist < d2){
      bool c1 = dist < d1, c0 = dist < d0;
      d2 = c1 ? d1 : dist;                 i2 = c1 ? i1 : s;
      float nd1 = c1 ? (c0 ? d0 : dist) : d1;
      int   ni1 = c1 ? (c0 ? i0 : s)    : i1;
      d0 = c0 ? dist : d0;                 i0 = c0 ? s : i0;
      d1 = nd1;                            i1 = ni1;
    }
  }
  pd[g][0][q]=d0; pd[g][1][q]=d1; pd[g][2][q]=d2;
  pi[g][0][q]=i0; pi[g][1][q]=i1; pi[g][2][q]=i2;
  __syncthreads();

  if (t < 64){
    float m0=3.4e38f, m1=3.4e38f, m2=3.4e38f;
    int   j0=0, j1=0, j2=0;
    #pragma unroll
    for (int gg = 0; gg < 8; ++gg){
      #pragma unroll
      for (int p = 0; p < 3; ++p){
        float dist = pd[gg][p][t]; int s = pi[gg][p][t];
        if (dist < m2){
          bool c1 = dist < m1, c0 = dist < m0;
          m2 = c1 ? m1 : dist;                 j2 = c1 ? j1 : s;
          float nd1 = c1 ? (c0 ? m0 : dist) : m1;
          int   ni1 = c1 ? (c0 ? j0 : s)    : j1;
          m0 = c0 ? dist : m0;                 j0 = c0 ? s : j0;
          m1 = nd1;                            j1 = ni1;
        }
      }
    }
    float r0 = 1.f/(m0 + 1e-8f), r1 = 1.f/(m1 + 1e-8f), r2 = 1.f/(m2 + 1e-8f);
    float rs = (r0 + r1) + r2;
    swts[0][t] = r0/rs; swts[1][t] = r1/rs; swts[2][t] = r2/rs;
    sidx[0][t] = j0;    sidx[1][t] = j1;    sidx[2][t] = j2;
  }
  __syncthreads();

  int w = t >> 6, lane = t & 63;
  for (int qq = w*8; qq < w*8 + 8; ++qq){
    float wa = swts[0][qq], wb = swts[1][qq], wc = swts[2][qq];
    int   j0 = sidx[0][qq], j1 = sidx[1][qq], j2 = sidx[2][qq];
    const ushort4 u0 = *(const ushort4*)(p2t + (((size_t)b*SPTS + j0)<<8) + (lane<<2));
    const ushort4 u1 = *(const ushort4*)(p2t + (((size_t)b*SPTS + j1)<<8) + (lane<<2));
    const ushort4 u2 = *(const ushort4*)(p2t + (((size_t)b*SPTS + j2)<<8) + (lane<<2));
    ushort4 ov;
    ov.x = f2bf(wa*bf2f(u0.x) + wb*bf2f(u1.x) + wc*bf2f(u2.x));
    ov.y = f2bf(wa*bf2f(u0.y) + wb*bf2f(u1.y) + wc*bf2f(u2.y));
    ov.z = f2bf(wa*bf2f(u0.z) + wb*bf2f(u1.z) + wc*bf2f(u2.z));
    ov.w = f2bf(wa*bf2f(u0.w) + wb*bf2f(u1.w) + wc*bf2f(u2.w));
    *(ushort4*)(X + ((size_t)b*NPTS + n0 + qq)*384 + 128 + (lane<<2)) = ov;
  }
}

// ======== GEMM1 (R14-best): BM=128, BN=256, BK=64, single-buffer (48KB -> 3 blocks/CU) ========
__global__ __launch_bounds__(256) void gemm1_k(const u16* __restrict__ A, const u16* __restrict__ Bw,
                                               u16* __restrict__ Cc,
                                               float* __restrict__ psum, float* __restrict__ psq){
  __shared__ u16 lA[128*64];     // 16 KB (sums/sqs alias after K-loop)
  __shared__ u16 lB[256*64];     // 32 KB (bounce alias after K-loop)
  float* sums = (float*)lA;
  float* sqs  = sums + 256;
  int t = threadIdx.x, lane = t & 63, wid = t >> 6;
  int rowBase = blockIdx.x << 7;            // 128 rows/block, grid 512
  int wm = wid >> 1, wn = wid & 1;

  const char* pA[4]; int dAo[4];
  #pragma unroll
  for (int j = 0; j < 4; ++j){
    int L = j*4096 + t*16;
    int row = L >> 7, kb = L & 127;
    int kbs = kb ^ ((row & 7) << 4);
    pA[j] = (const char*)A + (size_t)(rowBase + row)*768 + kbs;
    dAo[j] = j*4096 + wid*1024;
  }
  const char* pB[8]; int dBo[8];
  #pragma unroll
  for (int j = 0; j < 8; ++j){
    int L = j*4096 + t*16;
    int row = L >> 7, kb = L & 127;
    int kbs = kb ^ ((row & 7) << 4);
    pB[j] = (const char*)Bw + (size_t)row*768 + kbs;
    dBo[j] = j*4096 + wid*1024;
  }

  f32x4 z = {0.f,0.f,0.f,0.f};
  f32x4 acc[4][8];
  #pragma unroll
  for (int m = 0; m < 4; ++m)
    #pragma unroll
    for (int n = 0; n < 8; ++n) acc[m][n] = z;

  #pragma unroll
  for (int kt = 0; kt < 6; ++kt){
    size_t ko = (size_t)kt * 128;
    #pragma unroll
    for (int j = 0; j < 4; ++j) G2L(pA[j] + ko, (char*)lA + dAo[j]);
    #pragma unroll
    for (int j = 0; j < 8; ++j) G2L(pB[j] + ko, (char*)lB + dBo[j]);
    __syncthreads();
    #pragma unroll
    for (int ks = 0; ks < 2; ++ks){
      bf16x8 af[4];
      #pragma unroll
      for (int m = 0; m < 4; ++m){
        int row = wm*64 + m*16 + (lane & 15);
        int sw = (row & 7) << 4;
        int kb = (ks*64 + ((lane >> 4) << 4)) ^ sw;
        af[m] = *(const bf16x8*)((const char*)lA + row*128 + kb);
      }
      #pragma unroll
      for (int n = 0; n < 8; ++n){
        int row = wn*128 + n*16 + (lane & 15);
        int sw = (row & 7) << 4;
        int kb = (ks*64 + ((lane >> 4) << 4)) ^ sw;
        bf16x8 bv = *(const bf16x8*)((const char*)lB + row*128 + kb);
        #pragma unroll
        for (int m = 0; m < 4; ++m)
          acc[m][n] = __builtin_amdgcn_mfma_f32_16x16x32_bf16(af[m], bv, acc[m][n], 0, 0, 0);
      }
    }
    __syncthreads();
  }

  // ---- epilogue: stats (shfl-reduced, 2-way LDS atomics) then bounce in 2 row-halves ----
  sums[t] = 0.f; sqs[t] = 0.f;
  __syncthreads();
  int colb = wn*128 + (lane & 15);
  #pragma unroll
  for (int n = 0; n < 8; ++n){
    float s = 0.f, q = 0.f;
    #pragma unroll
    for (int m = 0; m < 4; ++m){
      #pragma unroll
      for (int r = 0; r < 4; ++r){
        float v = acc[m][n][r];
        s += v; q += v*v;
      }
    }
    s += __shfl_xor(s, 16); s += __shfl_xor(s, 32);
    q += __shfl_xor(q, 16); q += __shfl_xor(q, 32);
    if (lane < 16){
      atomicAdd(&sums[colb + n*16], s);
      atomicAdd(&sqs [colb + n*16], q);
    }
  }
  __syncthreads();
  psum[(size_t)blockIdx.x*256 + t] = sums[t];
  psq [(size_t)blockIdx.x*256 + t] = sqs[t];

  u16* bb = lB;                               // 32 KB = [64][256] bf16
  int rl0 = ((lane >> 4) << 2);
  #pragma unroll
  for (int h = 0; h < 2; ++h){
    __syncthreads();
    if (wm == h){
      #pragma unroll
      for (int m = 0; m < 4; ++m)
        #pragma unroll
        for (int n = 0; n < 8; ++n)
          #pragma unroll
          for (int r = 0; r < 4; ++r)
            bb[(m*16 + rl0 + r)*256 + colb + n*16] = f2bf(acc[m][n][r]);
    }
    __syncthreads();
    u16* dst = Cc + (size_t)(rowBase + h*64)*256;
    #pragma unroll
    for (int i = 0; i < 8; ++i)
      *(u16x8*)(dst + i*2048 + t*8) = *(const u16x8*)(bb + i*2048 + t*8);
  }
}

// ======== GEMM2 (R14-best): BM=128, BN=128, BK=64, single-buffer (33KB -> 4 blocks/CU); fused BN1+relu ========
__global__ __launch_bounds__(256) void gemm2_k(const u16* __restrict__ A, const u16* __restrict__ Bw,
                                               u16* __restrict__ Cc,
                                               const float* __restrict__ sc, const float* __restrict__ sh,
                                               float* __restrict__ psum, float* __restrict__ psq){
  const int K = 256;
  __shared__ u16 L[16384];                    // 32 KB: lA = L[0:8192], lB = L[8192:16384]; bounce = all
  __shared__ float sums[128], sqs[128];
  int t = threadIdx.x, lane = t & 63, wid = t >> 6;
  int rowBase = blockIdx.x << 7;              // 128 rows/block, grid 512
  int wm = wid >> 1, wn = wid & 1;

  const char* pB[4]; int dBo[4];
  #pragma unroll
  for (int j = 0; j < 4; ++j){
    int Lo = j*4096 + t*16;
    int row = Lo >> 7, kb = Lo & 127;
    int kbs = kb ^ ((row & 7) << 4);
    pB[j] = (const char*)Bw + ((size_t)row*K)*2 + kbs;
    dBo[j] = 16384 + j*4096 + wid*1024;       // byte offset into L
  }
  // A fused staging: row = t&127, half h = t>>7 (wave-uniform) -> 32 ch/thread/kt
  int arow = t & 127, h = t >> 7;
  const u16* pArow = A + (size_t)(rowBase + arow)*K + h*32;
  int asw = (arow & 7) << 4;
  int wAo0 = arow*128 + ((h*64      ) ^ asw);
  int wAo1 = arow*128 + ((h*64 + 16 ) ^ asw);
  int wAo2 = arow*128 + ((h*64 + 32 ) ^ asw);
  int wAo3 = arow*128 + ((h*64 + 48 ) ^ asw);

  f32x4 z = {0.f,0.f,0.f,0.f};
  f32x4 acc[4][4];
  #pragma unroll
  for (int m = 0; m < 4; ++m)
    #pragma unroll
    for (int n = 0; n < 4; ++n) acc[m][n] = z;

  for (int kk = 0; kk < K; kk += 64){
    size_t ko = (size_t)kk * 2;
    #pragma unroll
    for (int j = 0; j < 4; ++j) G2L(pB[j] + ko, (char*)L + dBo[j]);
    u16x8 y0 = *(const u16x8*)(pArow + kk);
    u16x8 y1 = *(const u16x8*)(pArow + kk + 8);
    u16x8 y2 = *(const u16x8*)(pArow + kk + 16);
    u16x8 y3 = *(const u16x8*)(pArow + kk + 24);
    int k0 = kk + h*32;                        // wave-uniform
    bf16x8 o0, o1, o2, o3;
    #pragma unroll
    for (int j = 0; j < 8; ++j){
      float v = bf2f((u16)y0[j]) * sc[k0 + j] + sh[k0 + j];
      o0[j] = (short)f2bf(fmaxf(v, 0.f));
    }
    #pragma unroll
    for (int j = 0; j < 8; ++j){
      float v = bf2f((u16)y1[j]) * sc[k0 + 8 + j] + sh[k0 + 8 + j];
      o1[j] = (short)f2bf(fmaxf(v, 0.f));
    }
    #pragma unroll
    for (int j = 0; j < 8; ++j){
      float v = bf2f((u16)y2[j]) * sc[k0 + 16 + j] + sh[k0 + 16 + j];
      o2[j] = (short)f2bf(fmaxf(v, 0.f));
    }
    #pragma unroll
    for (int j = 0; j < 8; ++j){
      float v = bf2f((u16)y3[j]) * sc[k0 + 24 + j] + sh[k0 + 24 + j];
      o3[j] = (short)f2bf(fmaxf(v, 0.f));
    }
    *(bf16x8*)((char*)L + wAo0) = o0;
    *(bf16x8*)((char*)L + wAo1) = o1;
    *(bf16x8*)((char*)L + wAo2) = o2;
    *(bf16x8*)((char*)L + wAo3) = o3;
    __syncthreads();
    #pragma unroll
    for (int ks = 0; ks < 2; ++ks){
      bf16x8 af[4];
      #pragma unroll
      for (int m = 0; m < 4; ++m){
        int row = wm*64 + m*16 + (lane & 15);
        int sw = (row & 7) << 4;
        int kb = (ks*64 + ((lane >> 4) << 4)) ^ sw;
        af[m] = *(const bf16x8*)((const char*)L + row*128 + kb);
      }
      #pragma unroll
      for (int n = 0; n < 4; ++n){
        int row = wn*64 + n*16 + (lane & 15);
        int sw = (row & 7) << 4;
        int kb = (ks*64 + ((lane >> 4) << 4)) ^ sw;
        bf16x8 bv = *(const bf16x8*)((const char*)L + 16384 + row*128 + kb);
        #pragma unroll
        for (int m = 0; m < 4; ++m)
          acc[m][n] = __builtin_amdgcn_mfma_f32_16x16x32_bf16(af[m], bv, acc[m][n], 0, 0, 0);
      }
    }
    __syncthreads();
  }

  // ---- epilogue: stats + full-tile bounce (L = 32KB = [128][128] bf16) ----
  if (t < 128){ sums[t] = 0.f; sqs[t] = 0.f; }
  __syncthreads();
  int colb = wn*64 + (lane & 15);
  int rl0 = ((lane >> 4) << 2);
  #pragma unroll
  for (int n = 0; n < 4; ++n){
    float s = 0.f, q = 0.f;
    #pragma unroll
    for (int m = 0; m < 4; ++m){
      #pragma unroll
      for (int r = 0; r < 4; ++r){
        float v = acc[m][n][r];
        L[(wm*64 + m*16 + rl0 + r)*128 + colb + n*16] = f2bf(v);
        s += v; q += v*v;
      }
    }
    s += __shfl_xor(s, 16); s += __shfl_xor(s, 32);
    q += __shfl_xor(q, 16); q += __shfl_xor(q, 32);
    if (lane < 16){
      atomicAdd(&sums[colb + n*16], s);
      atomicAdd(&sqs [colb + n*16], q);
    }
  }
  __syncthreads();
  if (t < 128){
    psum[(size_t)blockIdx.x*128 + t] = sums[t];
    psq [(size_t)blockIdx.x*128 + t] = sqs[t];
  }
  u16* dst = Cc + (size_t)rowBase*128;
  #pragma unroll
  for (int i = 0; i < 8; ++i)
    *(u16x8*)(dst + i*2048 + t*8) = *(const u16x8*)(L + i*2048 + t*8);
}

// ---------------- reduce partials [bid][ch] -> per-channel BN scale/shift (8 ch per block) ----------------
__global__ __launch_bounds__(256) void finalize2_k(const float* __restrict__ psum, const float* __restrict__ psq,
                                                   const float* __restrict__ g, const float* __restrict__ bet,
                                                   float* __restrict__ sc, float* __restrict__ sh,
                                                   int C, int NBLK){
  __shared__ float ls[256][8], lq[256][8];
  int c0 = blockIdx.x*8, t = threadIdx.x;
  float s[8], q[8];
  #pragma unroll
  for (int j = 0; j < 8; ++j){ s[j] = 0.f; q[j] = 0.f; }
  for (int rb = t; rb < NBLK; rb += 256){
    const float* ps = psum + (size_t)rb*C + c0;
    const float* pq = psq  + (size_t)rb*C + c0;
    #pragma unroll
    for (int j = 0; j < 8; ++j){ s[j] += ps[j]; q[j] += pq[j]; }
  }
  #pragma unroll
  for (int j = 0; j < 8; ++j){ ls[t][j] = s[j]; lq[t][j] = q[j]; }
  __syncthreads();
  for (int off = 128; off; off >>= 1){
    if (t < off){
      #pragma unroll
      for (int j = 0; j < 8; ++j){ ls[t][j] += ls[t+off][j]; lq[t][j] += lq[t+off][j]; }
    }
    __syncthreads();
  }
  if (t < 8){
    int c = c0 + t;
    const float inv = 1.f/65536.f;
    float mean = ls[0][t]*inv;
    float var  = lq[0][t]*inv - mean*mean;
    float rstd = rsqrtf(var + 1e-5f);
    float scl  = g[c]*rstd;
    sc[c] = scl;
    sh[c] = bet[c] - mean*scl;
  }
}

// ---------------- BN2 + relu + transpose (BN,128) -> (B,128,N) fp32 out ----------------
__global__ __launch_bounds__(256) void finalout_k(const u16* __restrict__ y2, const float* __restrict__ sc,
                                                  const float* __restrict__ sh, float* __restrict__ out){
  __shared__ float tl[128][65];
  int t  = threadIdx.x;
  int b  = blockIdx.x >> 6;
  int n0 = (blockIdx.x & 63) << 6;
  for (int i = t; i < 8192; i += 256){
    int r = i >> 7, c = i & 127;
    float v = bf2f(y2[((size_t)b*NPTS + n0 + r)*128 + c]);
    v = fmaxf(v*sc[c] + sh[c], 0.f);
    tl[c][r] = v;
  }
  __syncthreads();
  for (int i = t; i < 8192; i += 256){
    int o = i >> 6, j = i & 63;
    out[(size_t)b*128*NPTS + (size_t)o*NPTS + n0 + j] = tl[o][j];
  }
}

extern "C" void kernel_launch(void* const* d_in, const int* in_sizes, int n_in,
                              void* d_out, int out_size, void* d_ws, size_t ws_size,
                              hipStream_t stream) {
  const float* xyz1    = (const float*)d_in[0];
  const float* xyz2    = (const float*)d_in[1];
  const float* points1 = (const float*)d_in[2];
  const float* points2 = (const float*)d_in[3];
  const float* w1      = (const float*)d_in[4];
  // d_in[5] = b1 (cancels in BN)
  const float* g1      = (const float*)d_in[6];
  const float* beta1   = (const float*)d_in[7];
  const float* w2      = (const float*)d_in[8];
  // d_in[9] = b2 (cancels in BN)
  const float* g2      = (const float*)d_in[10];
  const float* beta2   = (const float*)d_in[11];

  char* ws = (char*)d_ws;
  u16*  X    = (u16*)ws;                          // BN x 384 bf16 = 50,331,648   (dead after gemm1)
  u16*  Y2   = (u16*)ws;                          // alias X: BN x 128 bf16
  u16*  Y1   = (u16*)(ws + 50331648);             // BN x 256 bf16 = 33,554,432
  u16*  p2t  = (u16*)(ws + 83886080);             // B x S x 256 bf16 = 8,388,608 (dead after knn)
  u16*  w1b  = (u16*)(ws + 92274688);             // 196,608
  u16*  w2b  = (u16*)(ws + 92471296);             // 65,536
  float* psum1 = (float*)(ws + 83886080);         // [512][256] = 512KB, alias p2t (dead after knn)
  float* psq1  = (float*)(ws + 84934656);         // 512KB
  float* psum2 = (float*)(ws + 85983232);         // [512][128] = 256KB
  float* psq2  = (float*)(ws + 86507520);         // 256KB
  float* sc1   = (float*)(ws + 87031808);
  float* sh1   = (float*)(ws + 87032832);
  float* sc2   = (float*)(ws + 87033856);
  float* sh2   = (float*)(ws + 87034368);

  convw_k<<<512, 256, 0, stream>>>(w1, w2, w1b, w2b);
  transpose_k<<<dim3(64, 16), 256, 0, stream>>>(points1, X,   128, NPTS, 384);
  transpose_k<<<dim3(16, 16), 256, 0, stream>>>(points2, p2t, 256, SPTS, 256);
  knn_k<<<1024, 512, 0, stream>>>(xyz1, xyz2, p2t, X);
  gemm1_k<<<512, 256, 0, stream>>>(X, w1b, Y1, psum1, psq1);
  finalize2_k<<<32, 256, 0, stream>>>(psum1, psq1, g1, beta1, sc1, sh1, 256, 512);
  gemm2_k<<<512, 256, 0, stream>>>(Y1, w2b, Y2, sc1, sh1, psum2, psq2);
  finalize2_k<<<16, 256, 0, stream>>>(psum2, psq2, g2, beta2, sc2, sh2, 128, 512);
  finalout_k<<<1024, 256, 0, stream>>>(Y2, sc2, sh2, (float*)d_out);
}